// Round 13
// baseline (357.279 us; speedup 1.0000x reference)
//
#include <hip/hip_runtime.h>
#include <math.h>

#define VOCABN 100000
#define EMBD 300
#define HID 128
#define NQ 32
#define NTOP 10

#define NCHS 19             // chunks scored, 16 k each (k 0..303, tail zero-padded)
#define NCHT 20             // chunks in W fragment table
#define CMIN 3
#define CAPA 43691
#define NBLK 256
#define NTHR 256
#define NWAVES (NBLK * 4)
#define GRID_F ((VOCABN + 31) / 32)   // 3125 fallback tiles

typedef __attribute__((ext_vector_type(8))) short bf16x8;
typedef __attribute__((ext_vector_type(4))) float f32x4;
typedef __attribute__((ext_vector_type(16))) float f32x16;
typedef __attribute__((ext_vector_type(4))) unsigned int u32x4;

__device__ __forceinline__ void split8(const f32x4 a, const f32x4 b,
                                       u32x4* hi, u32x4* lo) {
    float ef[8] = {a.x, a.y, a.z, a.w, b.x, b.y, b.z, b.w};
    unsigned int hw[8], lw[8];
#pragma unroll
    for (int j = 0; j < 8; ++j) {
        unsigned int u = __float_as_uint(ef[j]);
        hw[j] = u >> 16;
        float r = __uint_as_float(u & 0xffff0000u);
        lw[j] = __float_as_uint(ef[j] - r) >> 16;
    }
    *hi = (u32x4){hw[0] | (hw[1] << 16), hw[2] | (hw[3] << 16),
                  hw[4] | (hw[5] << 16), hw[6] | (hw[7] << 16)};
    *lo = (u32x4){lw[0] | (lw[1] << 16), lw[2] | (lw[3] << 16),
                  lw[4] | (lw[5] << 16), lw[6] | (lw[7] << 16)};
}

__device__ __forceinline__ bool tbetter(float w1, int i1, float w2, int i2) {
    return w1 > w2 || (w1 == w2 && i1 < i2);
}

__device__ __forceinline__ void lds_insert(float* mw, int* mid, int t, float w, int id) {
    const int b = t * NTOP;
    if (!tbetter(w, id, mw[b + NTOP - 1], mid[b + NTOP - 1])) return;
    int p = NTOP - 1;
    while (p > 0 && tbetter(w, id, mw[b + p - 1], mid[b + p - 1])) {
        mw[b + p] = mw[b + p - 1]; mid[b + p] = mid[b + p - 1]; --p;
    }
    mw[b + p] = w; mid[b + p] = id;
}

// device-scope grid barrier: cumulative counter zeroed by host memset each call.
// Same release/acquire + cache-maintenance pattern grid.sync() uses (validated r9).
__device__ __forceinline__ void gbar(int* ctr, int phase) {
    __syncthreads();
    if (threadIdx.x == 0) {
        __threadfence();                               // release: flush prior writes
        atomicAdd(ctr, 1);
        const int tgt = NBLK * phase;
        while (__hip_atomic_load(ctr, __ATOMIC_ACQUIRE, __HIP_MEMORY_SCOPE_AGENT) < tgt)
            __builtin_amdgcn_s_sleep(8);
        __threadfence();                               // acquire: invalidate local caches
    }
    __syncthreads();
}

// per-wave 32-row x 128-col bf16x3 MFMA scorer, tile-strided; depth-3 pipeline (proven r9/r12)
__device__ void score_tiles(int gw, int nwaves, const float* __restrict__ emb,
                            const unsigned short* __restrict__ wfH,
                            const unsigned short* __restrict__ wfL,
                            const float* __restrict__ qcbp,
                            const float* __restrict__ w2p, float b2,
                            const int* __restrict__ cand,
                            const int* __restrict__ ccnt,
                            const int* __restrict__ counts, int ncand,
                            float* __restrict__ taw, int* __restrict__ tai,
                            float* pvrow) {
    const int lane = threadIdx.x & 63;
    const int lrow = lane & 31;
    const int khalf = lane >> 5;
    const int ntile = (ncand + 31) >> 5;

    float qv[4], w2v[4];
#pragma unroll
    for (int t = 0; t < 4; ++t) {
        qv[t] = qcbp[t * 32 + lrow];
        w2v[t] = w2p[t * 32 + lrow];
    }

    for (int tile = gw; tile < ntile; tile += nwaves) {
        const int base = tile * 32;
        int ri = base + lrow;
        int rc = ri < ncand ? ri : ncand - 1;
        const long row = cand ? (long)cand[rc] : (long)rc;
        const float* ebase = emb + row * EMBD;

        f32x16 acc[4];
#pragma unroll
        for (int t = 0; t < 4; ++t)
#pragma unroll
            for (int r = 0; r < 16; ++r) acc[t][r] = 0.f;

        f32x4 e0[3], e1[3];
        u32x4 wh[3][4], wl[3][4];
        const f32x4 zf4 = (f32x4){0.f, 0.f, 0.f, 0.f};

#define LOADC(NN, S)                                                         \
    { int nn_ = (NN);                                                        \
      if (nn_ < NCHS) {                                                      \
          int k0_ = nn_ * 16 + khalf * 8;                                    \
          e0[S] = (k0_ + 4 <= EMBD) ? *(const f32x4*)(ebase + k0_) : zf4;    \
          e1[S] = (k0_ + 8 <= EMBD) ? *(const f32x4*)(ebase + k0_ + 4) : zf4;\
          _Pragma("unroll")                                                  \
          for (int t_ = 0; t_ < 4; ++t_) {                                   \
              long fo_ = ((long)(nn_ * 4 + t_) * 64 + lane) * 8;             \
              wh[S][t_] = *(const u32x4*)&wfH[fo_];                          \
              wl[S][t_] = *(const u32x4*)&wfL[fo_];                          \
          } } }

#define COMP(CC, S)                                                          \
    { if ((CC) < NCHS) {                                                     \
          union { bf16x8 v; u32x4 u; } eh_, el_;                             \
          split8(e0[S], e1[S], &eh_.u, &el_.u);                              \
          _Pragma("unroll")                                                  \
          for (int t_ = 0; t_ < 4; ++t_) {                                   \
              union { bf16x8 v; u32x4 u; } bh_, bl_;                         \
              bh_.u = wh[S][t_]; bl_.u = wl[S][t_];                          \
              acc[t_] = __builtin_amdgcn_mfma_f32_32x32x16_bf16(eh_.v, bh_.v, acc[t_], 0, 0, 0); \
              acc[t_] = __builtin_amdgcn_mfma_f32_32x32x16_bf16(eh_.v, bl_.v, acc[t_], 0, 0, 0); \
              acc[t_] = __builtin_amdgcn_mfma_f32_32x32x16_bf16(el_.v, bh_.v, acc[t_], 0, 0, 0); \
          } } }

        LOADC(0, 0) LOADC(1, 1) LOADC(2, 2)
        for (int g = 0; g < 7; ++g) {
            int c = g * 3;
            COMP(c + 0, 0) LOADC(c + 3, 0)
            COMP(c + 1, 1) LOADC(c + 4, 1)
            COMP(c + 2, 2) LOADC(c + 5, 2)
        }
#undef LOADC
#undef COMP

        float pr[16];
#pragma unroll
        for (int r = 0; r < 16; ++r) {
            float s = 0.f;
#pragma unroll
            for (int t = 0; t < 4; ++t) {
                float h = fmaxf(acc[t][r] + qv[t], 0.f);
                s += h * w2v[t];
            }
            s += __shfl_xor(s, 1); s += __shfl_xor(s, 2);
            s += __shfl_xor(s, 4); s += __shfl_xor(s, 8);
            s += __shfl_xor(s, 16);
            pr[r] = s;
        }
        if (lrow == 0) {
#pragma unroll
            for (int r = 0; r < 16; ++r)
                pvrow[(r & 3) + 8 * (r >> 2) + 4 * khalf] = pr[r];
        }
        asm volatile("s_waitcnt lgkmcnt(0)" ::: "memory");
        __builtin_amdgcn_sched_barrier(0);

        int gidx = base + lrow;
        float w = -1.f; int id = 0x7fffffff;
        if (gidx < ncand) {
            id = cand ? cand[gidx] : gidx;
            int cnt = cand ? ccnt[gidx] : counts[gidx];
            w = (float)cnt / (1.f + expf(-(pvrow[lrow] + b2)));
        }
        for (int r = 0; r < NTOP; ++r) {
            float bw = w; int bid = id;
#pragma unroll
            for (int m = 1; m < 32; m <<= 1) {
                float ow = __shfl_xor(bw, m); int oid = __shfl_xor(bid, m);
                if (ow > bw || (ow == bw && oid < bid)) { bw = ow; bid = oid; }
            }
            if (w == bw && id == bid) w = -2.f;
            if (lane == r) { taw[tile * NTOP + r] = bw; tai[tile * NTOP + r] = bid; }
        }
    }
}

__global__ void __launch_bounds__(NTHR, 1)   // full VGPR budget: no spill (r9 lesson)
k_mega(const int* __restrict__ qterms, const int* __restrict__ fdocs, int nflat,
       const float* __restrict__ emb, const float* __restrict__ sW1,
       const float* __restrict__ sb1, const float* __restrict__ sW2,
       const float* __restrict__ sb2, const float* __restrict__ eW1,
       const float* __restrict__ eb1, const float* __restrict__ eW2,
       const float* __restrict__ eb2, char* __restrict__ ws,
       float* __restrict__ out) {
    int* counts = (int*)ws;                                   // 400000 B
    int* ncA    = (int*)(ws + 400000);                        // 4  (zeroed with counts)
    int* flagp  = (int*)(ws + 400004);                        // 4  (zeroed with counts)
    float* qctx = (float*)(ws + 400064);
    float* qcb  = (float*)(ws + 401280);
    float* gtw  = (float*)(ws + 401792);
    int*   gti  = (int*)(ws + 401856);
    int* candA  = (int*)(ws + 402432);
    int* ccntA  = (int*)(ws + 577280);
    unsigned short* wfH = (unsigned short*)(ws + 752128);     // 81920
    unsigned short* wfL = (unsigned short*)(ws + 834048);     // 81920
    float* tawA = (float*)(ws + 915968);
    int*   taiA = (int*)(ws + 970624);
    float* tbw  = (float*)(ws + 1025280);
    int*   tbi  = (int*)(ws + 1150336);
    int*   bar  = (int*)(ws + 1275392);                       // zeroed by host memset node

    const int t = threadIdx.x;
    const int b = blockIdx.x;
    const int gid = b * NTHR + t;
    const int gstride = NBLK * NTHR;
    const int gw = b * 4 + (t >> 6);

    __shared__ float mw[NTHR * NTOP];
    __shared__ int   mid[NTHR * NTOP];
    __shared__ float pvs[4][32];
    __shared__ float qc[EMBD], em[EMBD], hbuf[HID];
    __shared__ int   qid[NQ];
    __shared__ int   top_id[NTOP];
    __shared__ int   s_nA, s_flag;

    // ---------- Phase A: zero counts+ncA+flag | W fragment table | qctx+qcb ----------
    for (int i = gid; i < VOCABN + 2; i += gstride) ((int*)ws)[i] = 0;
    if (gid < NCHT * 4 * 64) {   // 5120 fragment builders
        int c = gid >> 8;
        int rest = gid & 255;
        int tile = rest >> 6;
        int l = rest & 63;
        int col = tile * 32 + (l & 31);
        int kbase = c * 16 + (l >> 5) * 8;
        unsigned int hw[8], lw[8];
#pragma unroll
        for (int j = 0; j < 8; ++j) {
            int k = kbase + j;
            unsigned int hi = 0, lo = 0;
            if (k < EMBD) {
                float f = sW1[(long)k * HID + col];
                unsigned int u = __float_as_uint(f);
                hi = u >> 16;
                float r = __uint_as_float(u & 0xffff0000u);
                lo = __float_as_uint(f - r) >> 16;
            }
            hw[j] = hi; lw[j] = lo;
        }
        long fo = ((long)(c * 4 + tile) * 64 + l) * 8;
        *(u32x4*)&wfH[fo] = (u32x4){hw[0] | (hw[1] << 16), hw[2] | (hw[3] << 16),
                                    hw[4] | (hw[5] << 16), hw[6] | (hw[7] << 16)};
        *(u32x4*)&wfL[fo] = (u32x4){lw[0] | (lw[1] << 16), lw[2] | (lw[3] << 16),
                                    lw[4] | (lw[5] << 16), lw[6] | (lw[7] << 16)};
    }
    if (b == NBLK - 1) {
        if (t < NQ) qid[t] = qterms[t];
        __syncthreads();
        for (int i = t; i < EMBD; i += NTHR) {
            float s = 0.f;
            for (int q = 0; q < NQ; ++q) s += emb[(long)qid[q] * EMBD + i];
            float v = s * (1.0f / NQ);
            qc[i] = v; qctx[i] = v;
        }
        __syncthreads();
        int col = t >> 1, half = t & 1;
        float a = 0.f;
        int k0 = half * 150;
        for (int k = k0; k < k0 + 150; ++k)
            a += qc[k] * sW1[(long)(EMBD + k) * HID + col];
        a += __shfl_xor(a, 1);
        if (half == 0) qcb[col] = a + sb1[col];
    }
    gbar(bar, 1);

    // ---------- Phase B: histogram (512 KB of ids) ----------
    for (int i = gid; i < nflat; i += gstride)
        atomicAdd(&counts[fdocs[i]], 1);
    gbar(bar, 2);

    // ---------- Phase C: compact (count >= CMIN) ----------
    for (int i = gid; i < VOCABN; i += gstride) {
        int c = counts[i];
        if (c >= CMIN) {
            int p = atomicAdd(ncA, 1);
            if (p < CAPA) { candA[p] = i; ccntA[p] = c; }
        }
    }
    gbar(bar, 3);

    // ---------- Phase D: score A-candidates ----------
    if (t == 0) {
        int v = __hip_atomic_load(ncA, __ATOMIC_ACQUIRE, __HIP_MEMORY_SCOPE_AGENT);
        s_nA = v > CAPA ? CAPA : v;
    }
    __syncthreads();
    const int nA = s_nA;
    score_tiles(gw, NWAVES, emb, wfH, wfL, qcb, sW2, sb2[0],
                candA, ccntA, nullptr, nA, tawA, taiA, pvs[t >> 6]);
    gbar(bar, 4);

    // ---------- Phase E: merge A (block 0) + flag ----------
    if (b == 0) {
        int ntA = (nA + 31) >> 5;
#pragma unroll
        for (int n = 0; n < NTOP; ++n) { mw[t * NTOP + n] = -1.f; mid[t * NTOP + n] = 0x7fffffff; }
        for (int i = t; i < ntA * NTOP; i += NTHR)
            lds_insert(mw, mid, t, tawA[i], taiA[i]);
        for (int s = NTHR / 2; s > 0; s >>= 1) {
            __syncthreads();
            if (t < s) {
                const int ta = t * NTOP, tb = (t + s) * NTOP;
                float ow[NTOP]; int oid[NTOP];
                int i = 0, j = 0;
#pragma unroll
                for (int n = 0; n < NTOP; ++n) {
                    float wa = mw[ta + i]; int ia = mid[ta + i];
                    float wb = mw[tb + j]; int ib = mid[tb + j];
                    if (tbetter(wa, ia, wb, ib)) { ow[n] = wa; oid[n] = ia; ++i; }
                    else                         { ow[n] = wb; oid[n] = ib; ++j; }
                }
#pragma unroll
                for (int n = 0; n < NTOP; ++n) { mw[ta + n] = ow[n]; mid[ta + n] = oid[n]; }
            }
        }
        __syncthreads();
        if (t < NTOP) { gtw[t] = mw[t]; gti[t] = mid[t]; }
        if (t == 0) *flagp = (mw[NTOP - 1] > (float)(CMIN - 1)) ? 1 : 0;
    }
    gbar(bar, 5);

    // ---------- Phase F: conditional exact fallback (full vocab sweep) ----------
    if (t == 0) s_flag = __hip_atomic_load(flagp, __ATOMIC_ACQUIRE, __HIP_MEMORY_SCOPE_AGENT);
    __syncthreads();
    if (!s_flag)
        score_tiles(gw, NWAVES, emb, wfH, wfL, qcb, sW2, sb2[0],
                    nullptr, nullptr, counts, VOCABN, tbw, tbi, pvs[t >> 6]);
    gbar(bar, 6);

    // ---------- Phase G: final top-10 + expansion MLP (block 0) ----------
    if (b != 0) return;
    if (s_flag) {
        if (t < NTOP) {
            top_id[t] = gti[t];
            out[EMBD + t] = (float)gti[t];
            out[EMBD + NTOP + t] = gtw[t];
        }
    } else {
        const int ntB = GRID_F;
#pragma unroll
        for (int n = 0; n < NTOP; ++n) { mw[t * NTOP + n] = -1.f; mid[t * NTOP + n] = 0x7fffffff; }
        for (int i = t; i < ntB * NTOP; i += NTHR)
            lds_insert(mw, mid, t, tbw[i], tbi[i]);
        for (int s = NTHR / 2; s > 0; s >>= 1) {
            __syncthreads();
            if (t < s) {
                const int ta = t * NTOP, tb = (t + s) * NTOP;
                float ow[NTOP]; int oid[NTOP];
                int i = 0, j = 0;
#pragma unroll
                for (int n = 0; n < NTOP; ++n) {
                    float wa = mw[ta + i]; int ia = mid[ta + i];
                    float wb = mw[tb + j]; int ib = mid[tb + j];
                    if (tbetter(wa, ia, wb, ib)) { ow[n] = wa; oid[n] = ia; ++i; }
                    else                         { ow[n] = wb; oid[n] = ib; ++j; }
                }
#pragma unroll
                for (int n = 0; n < NTOP; ++n) { mw[ta + n] = ow[n]; mid[ta + n] = oid[n]; }
            }
        }
        __syncthreads();
        if (t < NTOP) {
            top_id[t] = mid[t];
            out[EMBD + t] = (float)mid[t];
            out[EMBD + NTOP + t] = mw[t];
        }
    }
    __syncthreads();

    for (int i = t; i < EMBD; i += NTHR) {
        float s = 0.f;
        for (int n = 0; n < NTOP; ++n) {
            long rid = top_id[n];
            if (rid > VOCABN - 1) rid = VOCABN - 1;
            s += emb[rid * EMBD + i];
        }
        em[i] = s * (1.0f / NTOP);
        qc[i] = qctx[i];
    }
    __syncthreads();

    {   // h = relu(feat . eW1 + eb1); 2 threads per col, K split 150 (proven r9)
        int col = t >> 1, ks = t & 1;
        float a = 0.f;
        int k0 = ks * 150, k1 = k0 + 150;
        for (int k = k0; k < k1; ++k) {
            float q = qc[k], e = em[k];
            a += q * eW1[(long)k * HID + col];
            a += e * eW1[(long)(EMBD + k) * HID + col];
            a += (q * e) * eW1[(long)(2 * EMBD + k) * HID + col];
        }
        a += __shfl_xor(a, 1);
        if (ks == 0) hbuf[col] = fmaxf(a + eb1[col], 0.f);
    }
    __syncthreads();

    for (int i = t; i < EMBD; i += NTHR) {
        float a = eb2[i];
        for (int j = 0; j < HID; ++j) a += hbuf[j] * eW2[(long)j * EMBD + i];
        out[i] = a;
    }
}

extern "C" void kernel_launch(void* const* d_in, const int* in_sizes, int n_in,
                              void* d_out, int out_size, void* d_ws, size_t ws_size,
                              hipStream_t stream) {
    const int* qterms  = (const int*)d_in[0];
    const int* fdocs   = (const int*)d_in[1];
    const float* emb   = (const float*)d_in[3];
    const float* sW1   = (const float*)d_in[4];
    const float* sb1   = (const float*)d_in[5];
    const float* sW2   = (const float*)d_in[6];
    const float* sb2   = (const float*)d_in[7];
    const float* eW1   = (const float*)d_in[8];
    const float* eb1   = (const float*)d_in[9];
    const float* eW2   = (const float*)d_in[10];
    const float* eb2   = (const float*)d_in[11];
    char* ws = (char*)d_ws;
    float* out = (float*)d_out;

    int nflat = in_sizes[1];

    // zero the grid-barrier counter (cold-start safe); everything else the kernel zeroes
    hipMemsetAsync(ws + 1275392, 0, 64, stream);
    k_mega<<<NBLK, NTHR, 0, stream>>>(qterms, fdocs, nflat, emb, sW1, sb1, sW2, sb2,
                                      eW1, eb1, eW2, eb2, ws, out);
}